// Round 12
// baseline (382.399 us; speedup 1.0000x reference)
//
#include <hip/hip_runtime.h>
#include <hip/hip_bf16.h>

#define H0 480
#define W0 640
#define H1 240
#define W1 320
#define H2 120
#define W2 160
#define H3 60
#define W3 80

// fp32 weight buffer offsets (in floats) inside d_ws
#define W_PW1T  0      // 5*32   [cin*32+o]
#define W_PW2T  160    // 32*64  [cin*64+o]
#define W_PW3T  2208   // 64*64  [cin*64+o]
#define W_DW3T  6304   // 9*64   [p*64+c]  (dw3 transposed)
#define WBUF_BYTES 65536

#define F2_PB (64 * H2 * W2)   // 1,228,800 (NHWC: [pix][64ch])
#define F3_PB (64 * H3 * W3)   //   307,200 (NCHW planes, unchanged)
#define N3    (H3 * W3)        //     4,800

// k_fuse12 tiling: each block computes a 32x8 f2-pixel tile via a shared f1 tile.
#define TH 8           // f2 tile height
#define TW 32          // f2 tile width
#define TILES_W 5      // W2/TW
#define TILES_H 15     // H2/TH
#define TILES_PB 75    // per batch
#define F1COLS 65      // 2*TW+1
#define NP 1105        // 17*65 f1 pixels per tile
#define LROW 66        // swizzled LDS row stride (33 even + 33 odd cols)
#define LCH 1122       // 17*66 floats per channel

typedef float v2f __attribute__((ext_vector_type(2)));

// ---------------- K0: transpose pointwise weights + dw3 ---------------------
__global__ __launch_bounds__(256) void k_cvt(
    const float* __restrict__ pw1, const float* __restrict__ pw2,
    const float* __restrict__ pw3, const float* __restrict__ dw3,
    float* __restrict__ wb)
{
    int t = threadIdx.x;
    for (int i = t; i < 160;  i += 256) { int o = i / 5,  c = i % 5;  wb[W_PW1T + c*32 + o] = pw1[i]; }
    for (int i = t; i < 2048; i += 256) { int o = i >> 5, c = i & 31; wb[W_PW2T + c*64 + o] = pw2[i]; }
    for (int i = t; i < 4096; i += 256) { int o = i >> 6, c = i & 63; wb[W_PW3T + c*64 + o] = pw3[i]; }
    for (int i = t; i < 576;  i += 256) { int p = i >> 6, c = i & 63; wb[W_DW3T + i] = dw3[c*9 + p]; }
}

// ---- A2/B chunk machinery (round-2 body; MASK only for border tiles) -------
template<bool MASK>
__device__ __forceinline__ void fuse12_chunks(
    int t, const float (&dd)[5][5], const float (&vmf)[5], const int (&widx)[5],
    float* __restrict__ f1buf, const float* __restrict__ wb,
    const float* __restrict__ b1, const float* __restrict__ dw2,
    int rbase, v2f (&acc2)[32])
{
    for (int cc = 0; cc < 4; cc++) {
        #pragma unroll
        for (int j = 0; j < 8; j++) {
            int c = cc*8 + j;
            float w10 = wb[W_PW1T + c];
            float w11 = wb[W_PW1T + 32 + c];
            float w12 = wb[W_PW1T + 64 + c];
            float w13 = wb[W_PW1T + 96 + c];
            float w14 = wb[W_PW1T + 128 + c];
            float bc = b1[c];
            #pragma unroll
            for (int i = 0; i < 5; i++) {
                float v = bc;
                v = fmaf(w10, dd[i][0], v);
                v = fmaf(w11, dd[i][1], v);
                v = fmaf(w12, dd[i][2], v);
                v = fmaf(w13, dd[i][3], v);
                v = fmaf(w14, dd[i][4], v);
                float f = v > 0.f ? v : (__expf(v) - 1.f);
                if (MASK) f *= vmf[i];             // border tiles only
                if (i < 4)               f1buf[j*LCH + widx[i]] = f;
                else if (t < NP - 1024)  f1buf[j*LCH + widx[4]] = f;   // t < 81
            }
        }
        __syncthreads();
        #pragma unroll
        for (int j = 0; j < 8; j++) {
            int c = cc*8 + j;
            const float* w9 = dw2 + c*9;               // uniform
            const float* fp = f1buf + j*LCH + rbase;
            float dv = 0.f;
            #pragma unroll
            for (int r = 0; r < 3; r++) {
                // tap cols 2*lc+{0,1,2} -> swizzled offsets {0, 33, 1}
                dv = fmaf(w9[r*3+0], fp[r*LROW],      dv);
                dv = fmaf(w9[r*3+1], fp[r*LROW + 33], dv);
                dv = fmaf(w9[r*3+2], fp[r*LROW + 1],  dv);
            }
            const v2f* wr2 = (const v2f*)(wb + W_PW2T + c*64);  // uniform
            v2f dvv = { dv, dv };
            #pragma unroll
            for (int o = 0; o < 32; o++)
                acc2[o] = __builtin_elementwise_fma(wr2[o], dvv, acc2[o]);  // v_pk_fma_f32
        }
        __syncthreads();
    }
}

// ---------------- K12: fused stage1+stage2, LDS-shared f1 tile ---------------
// r8 form (measured 118us local optimum). Only change: f2 written NHWC
// ([pix][64ch], 16 float4 contiguous per thread) so stage3's tap reads use
// full 64B lines. Write volume unchanged (tripwire: WRITE_SIZE 153,600KB).
__global__ __launch_bounds__(256, 3) void k_fuse12(
    const float* __restrict__ flow, const float* __restrict__ dw1,
    const float* __restrict__ b1, const float* __restrict__ dw2,
    const float* __restrict__ b2, const float* __restrict__ wb,
    float* __restrict__ out)
{
    __shared__ float f1buf[8 * LCH];   // 35,904 B

    const int t = threadIdx.x;
    const int bid = blockIdx.x;
    const int b = bid / TILES_PB;
    const int tile = bid - b * TILES_PB;
    const int oh0 = (tile / TILES_W) * TH;
    const int ow0 = (tile % TILES_W) * TW;

    const float sx = 2.f / (W0 - 1), sy = 2.f / (H0 - 1);

    float cs2[3], rs3[3], cs4[3], rs4[3];
    #pragma unroll
    for (int k = 0; k < 3; k++) {
        cs2[k] = dw1[18+k]   + dw1[21+k]   + dw1[24+k];
        rs3[k] = dw1[27+3*k] + dw1[28+3*k] + dw1[29+3*k];
        cs4[k] = dw1[36+k]   + dw1[39+k]   + dw1[42+k];
        rs4[k] = dw1[36+3*k] + dw1[37+3*k] + dw1[38+3*k];
    }
    const float ax2 = 2.f * sx, ay2 = 2.f * sy;
    float ex[3], fyc[3];
    #pragma unroll
    for (int k = 0; k < 3; k++) { ex[k] = sx*(float)(k-1) - 1.f; fyc[k] = sy*(float)(k-1) - 1.f; }
    const float AX1 = ax2*(cs2[0]+cs2[1]+cs2[2]);
    const float AX0 = cs2[0]*ex[0]+cs2[1]*ex[1]+cs2[2]*ex[2];
    const float AY1 = ay2*(rs3[0]+rs3[1]+rs3[2]);
    const float AY0 = rs3[0]*fyc[0]+rs3[1]*fyc[1]+rs3[2]*fyc[2];
    const float GX2 = ax2*ax2*(cs4[0]+cs4[1]+cs4[2]);
    const float GX1 = 2.f*ax2*(cs4[0]*ex[0]+cs4[1]*ex[1]+cs4[2]*ex[2]);
    const float GX0 = cs4[0]*ex[0]*ex[0]+cs4[1]*ex[1]*ex[1]+cs4[2]*ex[2]*ex[2];
    const float GY2 = ay2*ay2*(rs4[0]+rs4[1]+rs4[2]);
    const float GY1 = 2.f*ay2*(rs4[0]*fyc[0]+rs4[1]*fyc[1]+rs4[2]*fyc[2]);
    const float GY0 = rs4[0]*fyc[0]*fyc[0]+rs4[1]*fyc[1]*fyc[1]+rs4[2]*fyc[2]*fyc[2];

    float dd[5][5];
    float vmf[5];
    int   widx[5];
    const float* fb0 = flow + (size_t)(b*2) * (H0*W0);
    const float* fb1 = fb0 + (size_t)(H0*W0);

    const bool interior = (oh0 > 0) && (ow0 > 0);   // block-uniform

    if (interior) {
        #pragma unroll
        for (int i = 0; i < 5; i++) {
            int p = t + i*256; if (p > NP-1) p = NP-1;      // only i==4 clamps
            int tr = p / F1COLS;
            int tc = p - tr * F1COLS;
            widx[i] = tr*LROW + (tc & 1)*33 + (tc >> 1);    // parity-split swizzle
            vmf[i] = 1.f;                                   // unused (MASK=false)
            int fr = 2*oh0 - 1 + tr;                        // >= 15
            int fc = 2*ow0 - 1 + tc;                        // >= 63
            const float* r0 = fb0 + (size_t)(2*fr - 1) * W0 + (2*fc - 1);
            const float* r1 = fb1 + (size_t)(2*fr - 1) * W0 + (2*fc - 1);
            float a0 = 0.f, a1 = 0.f;
            #pragma unroll
            for (int ky = 0; ky < 3; ky++)
                #pragma unroll
                for (int kx = 0; kx < 3; kx++) {
                    a0 = fmaf(dw1[ky*3+kx],   r0[ky*W0+kx], a0);
                    a1 = fmaf(dw1[9+ky*3+kx], r1[ky*W0+kx], a1);
                }
            dd[i][0] = a0; dd[i][1] = a1;
            float fcf = (float)fc, frf = (float)fr;
            dd[i][2] = fmaf(AX1, fcf, AX0);
            dd[i][3] = fmaf(AY1, frf, AY0);
            dd[i][4] = fmaf(fmaf(GX2, fcf, GX1), fcf, GX0)
                     + fmaf(fmaf(GY2, frf, GY1), frf, GY0);
        }
    } else {
        #pragma unroll
        for (int i = 0; i < 5; i++) {
            int p = t + i*256; if (p > NP-1) p = NP-1;      // only i==4 clamps
            int tr = p / F1COLS;
            int tc = p - tr * F1COLS;
            widx[i] = tr*LROW + (tc & 1)*33 + (tc >> 1);    // parity-split swizzle
            int fr = 2*oh0 - 1 + tr;
            int fc = 2*ow0 - 1 + tc;
            vmf[i] = (fr >= 0 && fc >= 0) ? 1.f : 0.f;
            if (fr >= 1 && fc >= 1) {
                const float* r0 = fb0 + (size_t)(2*fr - 1) * W0 + (2*fc - 1);
                const float* r1 = fb1 + (size_t)(2*fr - 1) * W0 + (2*fc - 1);
                float a0 = 0.f, a1 = 0.f;
                #pragma unroll
                for (int ky = 0; ky < 3; ky++)
                    #pragma unroll
                    for (int kx = 0; kx < 3; kx++) {
                        a0 = fmaf(dw1[ky*3+kx],   r0[ky*W0+kx], a0);
                        a1 = fmaf(dw1[9+ky*3+kx], r1[ky*W0+kx], a1);
                    }
                dd[i][0] = a0; dd[i][1] = a1;
                float fcf = (float)fc, frf = (float)fr;
                dd[i][2] = fmaf(AX1, fcf, AX0);
                dd[i][3] = fmaf(AY1, frf, AY0);
                dd[i][4] = fmaf(fmaf(GX2, fcf, GX1), fcf, GX0)
                         + fmaf(fmaf(GY2, frf, GY1), frf, GY0);
            } else {
                int frc = fr < 0 ? 0 : fr, fcc = fc < 0 ? 0 : fc;
                int ih0 = 2*frc - 1, iw0 = 2*fcc - 1;
                float mh[3] = { ih0 >= 0 ? 1.f : 0.f, 1.f, 1.f };
                float mw[3] = { iw0 >= 0 ? 1.f : 0.f, 1.f, 1.f };
                int ihx[3] = { ih0 < 0 ? 0 : ih0, ih0 + 1, ih0 + 2 };
                int iwx[3] = { iw0 < 0 ? 0 : iw0, iw0 + 1, iw0 + 2 };
                float a0 = 0.f, a1 = 0.f;
                #pragma unroll
                for (int ky = 0; ky < 3; ky++) {
                    const float* rp0 = fb0 + (size_t)ihx[ky] * W0;
                    const float* rp1 = fb1 + (size_t)ihx[ky] * W0;
                    #pragma unroll
                    for (int kx = 0; kx < 3; kx++) {
                        float m = mh[ky]*mw[kx];
                        a0 = fmaf(dw1[ky*3+kx],   m * rp0[iwx[kx]], a0);
                        a1 = fmaf(dw1[9+ky*3+kx], m * rp1[iwx[kx]], a1);
                    }
                }
                dd[i][0] = a0; dd[i][1] = a1;
                float axv = 0.f, ayv = 0.f, arv = 0.f;
                #pragma unroll
                for (int ky = 0; ky < 3; ky++) {
                    float yv = fmaf((float)(ih0 + ky), sy, -1.f);
                    #pragma unroll
                    for (int kx = 0; kx < 3; kx++) {
                        float xv = fmaf((float)(iw0 + kx), sx, -1.f);
                        float m = mh[ky]*mw[kx];
                        axv = fmaf(dw1[18 + ky*3 + kx], m * xv, axv);
                        ayv = fmaf(dw1[27 + ky*3 + kx], m * yv, ayv);
                        arv = fmaf(dw1[36 + ky*3 + kx], m * (xv*xv + yv*yv), arv);
                    }
                }
                dd[i][2] = axv; dd[i][3] = ayv; dd[i][4] = arv;
            }
        }
    }

    v2f acc2[32];
    #pragma unroll
    for (int o = 0; o < 32; o++) acc2[o] = *(const v2f*)(b2 + 2*o);

    const int lr = t >> 5, lc = t & 31;        // this thread's f2 pixel in tile
    const int rbase = 2*lr*LROW + lc;          // swizzled LDS base for taps

    if (interior)
        fuse12_chunks<false>(t, dd, vmf, widx, f1buf, wb, b1, dw2, rbase, acc2);
    else
        fuse12_chunks<true>(t, dd, vmf, widx, f1buf, wb, b1, dw2, rbase, acc2);

    // ---- NHWC epilogue: this pixel's 64 channels contiguous (16 float4) ----
    const int oh = oh0 + lr, ow = ow0 + lc;
    float4* op = (float4*)(out + ((size_t)b*(H2*W2) + (size_t)oh*W2 + ow) * 64);
    #pragma unroll
    for (int q = 0; q < 16; q++) {
        float a0 = acc2[2*q].x,   a1 = acc2[2*q].y;
        float a2 = acc2[2*q+1].x, a3 = acc2[2*q+1].y;
        float4 v;
        v.x = a0 > 0.f ? a0 : (__expf(a0) - 1.f);
        v.y = a1 > 0.f ? a1 : (__expf(a1) - 1.f);
        v.z = a2 > 0.f ? a2 : (__expf(a2) - 1.f);
        v.w = a3 > 0.f ? a3 : (__expf(a3) - 1.f);
        op[q] = v;
    }
}

// ---------------- K3: dwsep3 + ELU + attn logits, NHWC input ----------------
// f2 is NHWC: each tap pixel = 256B contiguous = 4 full 64B lines -> 100%
// line utilization (vs ~50% with NCHW stride-8B lane pattern). Fetched bytes
// halve; r4/r11 showed stage3 pays per fetched byte. 4 channel-chunks keep
// live regs bounded (dv2[8] + acc2[32] + 4-float4 transient). Chain order
// per channel and per c matches r8 (m9 in {0,1} -> weight-fold bit-exact).
__global__ __launch_bounds__(256, 4) void k_stage3(
    const float* __restrict__ in, const float* __restrict__ b3,
    const float* __restrict__ wb,
    const float* __restrict__ attn_w, const float* __restrict__ attn_b,
    float* __restrict__ out, float* __restrict__ lg)
{
    int idx = blockIdx.x * 256 + threadIdx.x;     // 153,600 exact
    int ow = idx % W3; int tmp = idx / W3; int oh = tmp % H3; int b = tmp / H3;
    int ih0 = 2*oh - 1, iw0 = 2*ow - 1;
    float mh[3] = { ih0 >= 0 ? 1.f : 0.f, 1.f, 1.f };
    float mw[3] = { iw0 >= 0 ? 1.f : 0.f, 1.f, 1.f };
    int ihx[3] = { ih0 < 0 ? 0 : ih0, ih0 + 1, ih0 + 2 };
    int iwx[3] = { iw0 < 0 ? 0 : iw0, iw0 + 1, iw0 + 2 };
    float m9[9];
    int off[9];                                    // float offsets (pix*64)
    #pragma unroll
    for (int ky = 0; ky < 3; ky++)
        #pragma unroll
        for (int kx = 0; kx < 3; kx++) {
            m9[ky*3 + kx] = mh[ky] * mw[kx];
            off[ky*3 + kx] = (ihx[ky]*W2 + iwx[kx]) * 64;
        }

    v2f acc2[32];
    #pragma unroll
    for (int o = 0; o < 32; o++) acc2[o] = *(const v2f*)(b3 + 2*o);

    const float* inb = in + (size_t)b * F2_PB;

    #pragma unroll
    for (int ck = 0; ck < 4; ck++) {               // channels [16ck, 16ck+16)
        v2f dv2[8];
        #pragma unroll
        for (int j = 0; j < 8; j++) dv2[j] = (v2f){0.f, 0.f};

        #pragma unroll
        for (int p = 0; p < 9; p++) {
            const float4* tp = (const float4*)(inb + (size_t)off[p] + 16*ck);
            float4 t0 = tp[0], t1 = tp[1], t2 = tp[2], t3 = tp[3];  // one 64B line
            float mp = m9[p];
            const v2f* wt = (const v2f*)(wb + W_DW3T + p*64 + 16*ck);  // uniform
            v2f tv0 = {t0.x, t0.y}, tv1 = {t0.z, t0.w};
            v2f tv2 = {t1.x, t1.y}, tv3 = {t1.z, t1.w};
            v2f tv4 = {t2.x, t2.y}, tv5 = {t2.z, t2.w};
            v2f tv6 = {t3.x, t3.y}, tv7 = {t3.z, t3.w};
            dv2[0] = __builtin_elementwise_fma(wt[0]*mp, tv0, dv2[0]);
            dv2[1] = __builtin_elementwise_fma(wt[1]*mp, tv1, dv2[1]);
            dv2[2] = __builtin_elementwise_fma(wt[2]*mp, tv2, dv2[2]);
            dv2[3] = __builtin_elementwise_fma(wt[3]*mp, tv3, dv2[3]);
            dv2[4] = __builtin_elementwise_fma(wt[4]*mp, tv4, dv2[4]);
            dv2[5] = __builtin_elementwise_fma(wt[5]*mp, tv5, dv2[5]);
            dv2[6] = __builtin_elementwise_fma(wt[6]*mp, tv6, dv2[6]);
            dv2[7] = __builtin_elementwise_fma(wt[7]*mp, tv7, dv2[7]);
        }
        // matvec: these 16 channels into acc2 (c ascending, matching r8)
        #pragma unroll
        for (int j = 0; j < 8; j++) {
            int c = 16*ck + 2*j;
            const v2f* wrA = (const v2f*)(wb + W_PW3T + c*64);        // uniform
            const v2f* wrB = (const v2f*)(wb + W_PW3T + (c+1)*64);
            v2f da = { dv2[j].x, dv2[j].x };
            v2f db = { dv2[j].y, dv2[j].y };
            #pragma unroll
            for (int o = 0; o < 32; o++) {
                acc2[o] = __builtin_elementwise_fma(wrA[o], da, acc2[o]);  // v_pk_fma_f32
                acc2[o] = __builtin_elementwise_fma(wrB[o], db, acc2[o]);
            }
        }
    }

    size_t obase = ((size_t)b * 64) * (H3*W3) + (size_t)oh*W3 + ow;
    float logit = attn_b[0];
    #pragma unroll
    for (int o = 0; o < 32; o++) {
        float va = acc2[o].x, vb2 = acc2[o].y;
        float ea = va  > 0.f ? va  : (__expf(va)  - 1.f);
        float eb = vb2 > 0.f ? vb2 : (__expf(vb2) - 1.f);
        out[obase + (size_t)(2*o)  *(H3*W3)] = ea;
        out[obase + (size_t)(2*o+1)*(H3*W3)] = eb;
        logit = fmaf(attn_w[2*o],   ea, logit);    // attn_w: uniform s_loads
        logit = fmaf(attn_w[2*o+1], eb, logit);
    }
    lg[b*N3 + oh*W3 + ow] = logit;                 // coalesced per wave
}

// ---------------- K4a: per-batch softmax over logits ------------------------
__global__ __launch_bounds__(256) void k_softmax(
    float* __restrict__ lg, float* __restrict__ invs)
{
    int b = blockIdx.x, t = threadIdx.x;
    int lane = t & 63, wid = t >> 6;       // 4 waves
    __shared__ float sm[4], ss[4];
    float* base = lg + b*N3;

    float m = -1e30f;
    for (int n = t; n < N3; n += 256) m = fmaxf(m, base[n]);
    #pragma unroll
    for (int o = 32; o; o >>= 1) m = fmaxf(m, __shfl_down(m, o, 64));
    if (lane == 0) sm[wid] = m;
    __syncthreads();
    m = fmaxf(fmaxf(sm[0], sm[1]), fmaxf(sm[2], sm[3]));

    float s = 0.f;
    for (int n = t; n < N3; n += 256) {
        float e = __expf(base[n] - m);
        base[n] = e;
        s += e;
    }
    #pragma unroll
    for (int o = 32; o; o >>= 1) s += __shfl_down(s, o, 64);
    if (lane == 0) ss[wid] = s;
    __syncthreads();
    if (t == 0) invs[b] = 1.f / (ss[0] + ss[1] + ss[2] + ss[3]);
}

// ---------------- K4b: attention pooling, one block per (b,c) ---------------
__global__ __launch_bounds__(256) void k_pool(
    const float* __restrict__ f3, const float* __restrict__ lg,
    const float* __restrict__ invs, float* __restrict__ pooled)
{
    int bc = blockIdx.x;           // b*64 + c
    int b = bc >> 6, c = bc & 63;
    int t = threadIdx.x, lane = t & 63, wid = t >> 6;
    __shared__ float sr[4];

    const float4* f = (const float4*)(f3 + (size_t)b * F3_PB + (size_t)c * N3);
    const float4* w = (const float4*)(lg + b*N3);

    float s = 0.f;
    for (int i = t; i < N3/4; i += 256) {
        float4 a = f[i], e = w[i];
        s = fmaf(a.x, e.x, s); s = fmaf(a.y, e.y, s);
        s = fmaf(a.z, e.z, s); s = fmaf(a.w, e.w, s);
    }
    #pragma unroll
    for (int o = 32; o; o >>= 1) s += __shfl_down(s, o, 64);
    if (lane == 0) sr[wid] = s;
    __syncthreads();
    if (t == 0) pooled[bc] = (sr[0] + sr[1] + sr[2] + sr[3]) * invs[b];
}

// ---------------- K4c: MLP + GRU tail, one wave per batch -------------------
__global__ __launch_bounds__(64) void k_tail(
    const float* __restrict__ pooled,
    const float* __restrict__ mlp1_w, const float* __restrict__ mlp1_b,
    const float* __restrict__ mlp2_w, const float* __restrict__ mlp2_b,
    const float* __restrict__ w_ih, const float* __restrict__ b_ih,
    const float* __restrict__ b_hh,
    const float* __restrict__ fc_w, const float* __restrict__ fc_b,
    float* __restrict__ out)
{
    __shared__ float s_pooled[64];
    __shared__ float s_h1[32];
    __shared__ float s_om[3];
    __shared__ float s_h[32];
    int t = threadIdx.x, b = blockIdx.x;

    s_pooled[t] = pooled[b*64 + t];
    __syncthreads();

    if (t < 32) {
        float a = mlp1_b[t];
        #pragma unroll 8
        for (int c = 0; c < 64; c++) a = fmaf(mlp1_w[t*64 + c], s_pooled[c], a);
        s_h1[t] = a > 0.f ? a : (__expf(a) - 1.f);
    }
    __syncthreads();
    if (t < 3) {
        float a = mlp2_b[t];
        for (int j = 0; j < 32; j++) a = fmaf(mlp2_w[t*32 + j], s_h1[j], a);
        s_om[t] = a;
    }
    __syncthreads();
    if (t < 32) {
        float gr = b_ih[t], gz = b_ih[32 + t], gn = b_ih[64 + t];
        #pragma unroll
        for (int k = 0; k < 3; k++) {
            float ok = s_om[k];
            gr = fmaf(w_ih[t*3 + k],        ok, gr);
            gz = fmaf(w_ih[(32 + t)*3 + k], ok, gz);
            gn = fmaf(w_ih[(64 + t)*3 + k], ok, gn);
        }
        float hr = b_hh[t], hz = b_hh[32 + t], hn = b_hh[64 + t];
        float r = 1.f / (1.f + __expf(-(gr + hr)));
        float z = 1.f / (1.f + __expf(-(gz + hz)));
        float nn = tanhf(gn + r * hn);
        s_h[t] = (1.f - z) * nn;
    }
    __syncthreads();
    if (t < 3) {
        float dl = fc_b[t];
        for (int j = 0; j < 32; j++) dl = fmaf(fc_w[t*32 + j], s_h[j], dl);
        out[b*3 + t] = s_om[t] + dl;
    }
}

// ---------------- host ----------------
extern "C" void kernel_launch(void* const* d_in, const int* in_sizes, int n_in,
                              void* d_out, int out_size, void* d_ws, size_t ws_size,
                              hipStream_t stream)
{
    const float* flow = (const float*)d_in[0];
    float* wb = (float*)d_ws;

    // layout: [wbuf][f2 NHWC x32][f3 x32][logits 32x4800][invS 32][pooled 32*64]
    float* f2     = (float*)((char*)d_ws + WBUF_BYTES);
    float* f3     = f2 + (size_t)32 * F2_PB;
    float* lg     = f3 + (size_t)32 * F3_PB;
    float* invs   = lg + (size_t)32 * N3;
    float* pooled = invs + 32;

    k_cvt<<<1, 256, 0, stream>>>(
        (const float*)d_in[2], (const float*)d_in[5], (const float*)d_in[8],
        (const float*)d_in[7], wb);

    // fused stage1+stage2: one block per 32x8 f2 tile
    k_fuse12<<<32 * TILES_PB, 256, 0, stream>>>(
        flow, (const float*)d_in[1], (const float*)d_in[3],
        (const float*)d_in[4], (const float*)d_in[6], wb, f2);

    // stage3 + fused attn logits: one thread per f3 pixel (NHWC f2 input)
    k_stage3<<<(32*H3*W3)/256, 256, 0, stream>>>(
        f2, (const float*)d_in[9], wb,
        (const float*)d_in[10], (const float*)d_in[11], f3, lg);

    k_softmax<<<32, 256, 0, stream>>>(lg, invs);

    k_pool<<<32*64, 256, 0, stream>>>(f3, lg, invs, pooled);

    k_tail<<<32, 64, 0, stream>>>(pooled,
        (const float*)d_in[12], (const float*)d_in[13],
        (const float*)d_in[14], (const float*)d_in[15],
        (const float*)d_in[16], (const float*)d_in[18],
        (const float*)d_in[19], (const float*)d_in[20],
        (const float*)d_in[21], (float*)d_out);
}

// Round 13
// 309.712 us; speedup vs baseline: 1.2347x; 1.2347x over previous
//
#include <hip/hip_runtime.h>
#include <hip/hip_bf16.h>

#define H0 480
#define W0 640
#define H1 240
#define W1 320
#define H2 120
#define W2 160
#define H3 60
#define W3 80

// fp32 weight buffer offsets (in floats) inside d_ws  (transposed pointwise copies)
#define W_PW1T  0      // 5*32  [cin*32+o]
#define W_PW2T  160    // 32*64 [cin*64+o]
#define W_PW3T  2208   // 64*64 [cin*64+o]
#define WBUF_BYTES 65536

#define F2_PB (64 * H2 * W2)   // 1,228,800
#define F3_PB (64 * H3 * W3)   //   307,200
#define N3    (H3 * W3)        //     4,800

// k_fuse12 tiling: each block computes a 32x8 f2-pixel tile via a shared f1 tile.
#define TH 8           // f2 tile height
#define TW 32          // f2 tile width
#define TILES_W 5      // W2/TW
#define TILES_H 15     // H2/TH
#define TILES_PB 75    // per batch
#define F1COLS 65      // 2*TW+1
#define NP 1105        // 17*65 f1 pixels per tile
#define LROW 66        // swizzled LDS row stride (33 even + 33 odd cols)
#define LCH 1122       // 17*66 floats per channel

typedef float v2f __attribute__((ext_vector_type(2)));

// ---------------- K0: transpose pointwise weights ---------------------------
__global__ __launch_bounds__(256) void k_cvt(
    const float* __restrict__ pw1, const float* __restrict__ pw2,
    const float* __restrict__ pw3, float* __restrict__ wb)
{
    int t = threadIdx.x;
    for (int i = t; i < 160;  i += 256) { int o = i / 5,  c = i % 5;  wb[W_PW1T + c*32 + o] = pw1[i]; }
    for (int i = t; i < 2048; i += 256) { int o = i >> 5, c = i & 31; wb[W_PW2T + c*64 + o] = pw2[i]; }
    for (int i = t; i < 4096; i += 256) { int o = i >> 6, c = i & 63; wb[W_PW3T + c*64 + o] = pw3[i]; }
}

// ---- A2/B chunk machinery (round-2 body; MASK only for border tiles) -------
// A2: scalar pw1+ELU -> f1 to LDS (parity-split swizzle — r7: natural layout
//     + b64 reads RAISES conflicts; r12: NHWC stores uncoalesced, +20us).
// B : dw2 from LDS taps {0,33,1} + packed rank-1 pw2 update (v_pk_fma_f32).
// No weight caching across pixels — r7 showed +28 live VGPRs -> scratch spill.
// r10: LDS-staging the phase-A flow window also loses (+7us) — scattered
// global taps at 3 blocks/CU are already hidden by L1/L2 + TLP.
template<bool MASK>
__device__ __forceinline__ void fuse12_chunks(
    int t, const float (&dd)[5][5], const float (&vmf)[5], const int (&widx)[5],
    float* __restrict__ f1buf, const float* __restrict__ wb,
    const float* __restrict__ b1, const float* __restrict__ dw2,
    int rbase, v2f (&acc2)[32])
{
    for (int cc = 0; cc < 4; cc++) {
        #pragma unroll
        for (int j = 0; j < 8; j++) {
            int c = cc*8 + j;
            float w10 = wb[W_PW1T + c];
            float w11 = wb[W_PW1T + 32 + c];
            float w12 = wb[W_PW1T + 64 + c];
            float w13 = wb[W_PW1T + 96 + c];
            float w14 = wb[W_PW1T + 128 + c];
            float bc = b1[c];
            #pragma unroll
            for (int i = 0; i < 5; i++) {
                float v = bc;
                v = fmaf(w10, dd[i][0], v);
                v = fmaf(w11, dd[i][1], v);
                v = fmaf(w12, dd[i][2], v);
                v = fmaf(w13, dd[i][3], v);
                v = fmaf(w14, dd[i][4], v);
                float f = v > 0.f ? v : (__expf(v) - 1.f);
                if (MASK) f *= vmf[i];             // border tiles only
                if (i < 4)               f1buf[j*LCH + widx[i]] = f;
                else if (t < NP - 1024)  f1buf[j*LCH + widx[4]] = f;   // t < 81
            }
        }
        __syncthreads();
        #pragma unroll
        for (int j = 0; j < 8; j++) {
            int c = cc*8 + j;
            const float* w9 = dw2 + c*9;               // uniform
            const float* fp = f1buf + j*LCH + rbase;
            float dv = 0.f;
            #pragma unroll
            for (int r = 0; r < 3; r++) {
                // tap cols 2*lc+{0,1,2} -> swizzled offsets {0, 33, 1}
                dv = fmaf(w9[r*3+0], fp[r*LROW],      dv);
                dv = fmaf(w9[r*3+1], fp[r*LROW + 33], dv);
                dv = fmaf(w9[r*3+2], fp[r*LROW + 1],  dv);
            }
            const v2f* wr2 = (const v2f*)(wb + W_PW2T + c*64);  // uniform
            v2f dvv = { dv, dv };
            #pragma unroll
            for (int o = 0; o < 32; o++)
                acc2[o] = __builtin_elementwise_fma(wr2[o], dvv, acc2[o]);  // v_pk_fma_f32
        }
        __syncthreads();
    }
}

// ---------------- K12: fused stage1+stage2, LDS-shared f1 tile ---------------
// (256,3): 3 blocks/CU measured best (round-3 A/B: (256,4) = +27us).
// Block-uniform interior/border split: 56/75 tiles have all f1 px interior
// (oh0>0 && ow0>0 -> fr>=15, fc>=63) -> skip border branch + vmf multiplies.
// r8 form: measured 118us / VGPR 60 — verified local optimum (r3/r7/r10/r12
// neighbors all regressed).
__global__ __launch_bounds__(256, 3) void k_fuse12(
    const float* __restrict__ flow, const float* __restrict__ dw1,
    const float* __restrict__ b1, const float* __restrict__ dw2,
    const float* __restrict__ b2, const float* __restrict__ wb,
    float* __restrict__ out)
{
    __shared__ float f1buf[8 * LCH];   // 35,904 B

    const int t = threadIdx.x;
    const int bid = blockIdx.x;
    const int b = bid / TILES_PB;
    const int tile = bid - b * TILES_PB;
    const int oh0 = (tile / TILES_W) * TH;
    const int ow0 = (tile % TILES_W) * TW;

    const float sx = 2.f / (W0 - 1), sy = 2.f / (H0 - 1);

    // ---- uniform closed-form coefficients for coord-channel convs ----
    float cs2[3], rs3[3], cs4[3], rs4[3];
    #pragma unroll
    for (int k = 0; k < 3; k++) {
        cs2[k] = dw1[18+k]   + dw1[21+k]   + dw1[24+k];
        rs3[k] = dw1[27+3*k] + dw1[28+3*k] + dw1[29+3*k];
        cs4[k] = dw1[36+k]   + dw1[39+k]   + dw1[42+k];
        rs4[k] = dw1[36+3*k] + dw1[37+3*k] + dw1[38+3*k];
    }
    const float ax2 = 2.f * sx, ay2 = 2.f * sy;
    float ex[3], fyc[3];
    #pragma unroll
    for (int k = 0; k < 3; k++) { ex[k] = sx*(float)(k-1) - 1.f; fyc[k] = sy*(float)(k-1) - 1.f; }
    const float AX1 = ax2*(cs2[0]+cs2[1]+cs2[2]);
    const float AX0 = cs2[0]*ex[0]+cs2[1]*ex[1]+cs2[2]*ex[2];
    const float AY1 = ay2*(rs3[0]+rs3[1]+rs3[2]);
    const float AY0 = rs3[0]*fyc[0]+rs3[1]*fyc[1]+rs3[2]*fyc[2];
    const float GX2 = ax2*ax2*(cs4[0]+cs4[1]+cs4[2]);
    const float GX1 = 2.f*ax2*(cs4[0]*ex[0]+cs4[1]*ex[1]+cs4[2]*ex[2]);
    const float GX0 = cs4[0]*ex[0]*ex[0]+cs4[1]*ex[1]*ex[1]+cs4[2]*ex[2]*ex[2];
    const float GY2 = ay2*ay2*(rs4[0]+rs4[1]+rs4[2]);
    const float GY1 = 2.f*ay2*(rs4[0]*fyc[0]+rs4[1]*fyc[1]+rs4[2]*fyc[2]);
    const float GY0 = rs4[0]*fyc[0]*fyc[0]+rs4[1]*fyc[1]*fyc[1]+rs4[2]*fyc[2]*fyc[2];

    // ---- Phase A: d-vectors for 5 f1 pixels/thread ----
    float dd[5][5];
    float vmf[5];
    int   widx[5];
    const float* fb0 = flow + (size_t)(b*2) * (H0*W0);
    const float* fb1 = fb0 + (size_t)(H0*W0);

    const bool interior = (oh0 > 0) && (ow0 > 0);   // block-uniform

    if (interior) {
        #pragma unroll
        for (int i = 0; i < 5; i++) {
            int p = t + i*256; if (p > NP-1) p = NP-1;      // only i==4 clamps
            int tr = p / F1COLS;
            int tc = p - tr * F1COLS;
            widx[i] = tr*LROW + (tc & 1)*33 + (tc >> 1);    // parity-split swizzle
            vmf[i] = 1.f;                                   // unused (MASK=false)
            int fr = 2*oh0 - 1 + tr;                        // >= 15
            int fc = 2*ow0 - 1 + tc;                        // >= 63
            const float* r0 = fb0 + (size_t)(2*fr - 1) * W0 + (2*fc - 1);
            const float* r1 = fb1 + (size_t)(2*fr - 1) * W0 + (2*fc - 1);
            float a0 = 0.f, a1 = 0.f;
            #pragma unroll
            for (int ky = 0; ky < 3; ky++)
                #pragma unroll
                for (int kx = 0; kx < 3; kx++) {
                    a0 = fmaf(dw1[ky*3+kx],   r0[ky*W0+kx], a0);
                    a1 = fmaf(dw1[9+ky*3+kx], r1[ky*W0+kx], a1);
                }
            dd[i][0] = a0; dd[i][1] = a1;
            float fcf = (float)fc, frf = (float)fr;
            dd[i][2] = fmaf(AX1, fcf, AX0);
            dd[i][3] = fmaf(AY1, frf, AY0);
            dd[i][4] = fmaf(fmaf(GX2, fcf, GX1), fcf, GX0)
                     + fmaf(fmaf(GY2, frf, GY1), frf, GY0);
        }
    } else {
        #pragma unroll
        for (int i = 0; i < 5; i++) {
            int p = t + i*256; if (p > NP-1) p = NP-1;      // only i==4 clamps
            int tr = p / F1COLS;
            int tc = p - tr * F1COLS;
            widx[i] = tr*LROW + (tc & 1)*33 + (tc >> 1);    // parity-split swizzle
            int fr = 2*oh0 - 1 + tr;
            int fc = 2*ow0 - 1 + tc;
            vmf[i] = (fr >= 0 && fc >= 0) ? 1.f : 0.f;
            if (fr >= 1 && fc >= 1) {
                // interior pixel: mask-free taps + closed-form coords
                const float* r0 = fb0 + (size_t)(2*fr - 1) * W0 + (2*fc - 1);
                const float* r1 = fb1 + (size_t)(2*fr - 1) * W0 + (2*fc - 1);
                float a0 = 0.f, a1 = 0.f;
                #pragma unroll
                for (int ky = 0; ky < 3; ky++)
                    #pragma unroll
                    for (int kx = 0; kx < 3; kx++) {
                        a0 = fmaf(dw1[ky*3+kx],   r0[ky*W0+kx], a0);
                        a1 = fmaf(dw1[9+ky*3+kx], r1[ky*W0+kx], a1);
                    }
                dd[i][0] = a0; dd[i][1] = a1;
                float fcf = (float)fc, frf = (float)fr;
                dd[i][2] = fmaf(AX1, fcf, AX0);
                dd[i][3] = fmaf(AY1, frf, AY0);
                dd[i][4] = fmaf(fmaf(GX2, fcf, GX1), fcf, GX0)
                         + fmaf(fmaf(GY2, frf, GY1), frf, GY0);
            } else {
                // border pixel: original general masked path
                int frc = fr < 0 ? 0 : fr, fcc = fc < 0 ? 0 : fc;
                int ih0 = 2*frc - 1, iw0 = 2*fcc - 1;
                float mh[3] = { ih0 >= 0 ? 1.f : 0.f, 1.f, 1.f };
                float mw[3] = { iw0 >= 0 ? 1.f : 0.f, 1.f, 1.f };
                int ihx[3] = { ih0 < 0 ? 0 : ih0, ih0 + 1, ih0 + 2 };
                int iwx[3] = { iw0 < 0 ? 0 : iw0, iw0 + 1, iw0 + 2 };
                float a0 = 0.f, a1 = 0.f;
                #pragma unroll
                for (int ky = 0; ky < 3; ky++) {
                    const float* rp0 = fb0 + (size_t)ihx[ky] * W0;
                    const float* rp1 = fb1 + (size_t)ihx[ky] * W0;
                    #pragma unroll
                    for (int kx = 0; kx < 3; kx++) {
                        float m = mh[ky]*mw[kx];
                        a0 = fmaf(dw1[ky*3+kx],   m * rp0[iwx[kx]], a0);
                        a1 = fmaf(dw1[9+ky*3+kx], m * rp1[iwx[kx]], a1);
                    }
                }
                dd[i][0] = a0; dd[i][1] = a1;
                float axv = 0.f, ayv = 0.f, arv = 0.f;
                #pragma unroll
                for (int ky = 0; ky < 3; ky++) {
                    float yv = fmaf((float)(ih0 + ky), sy, -1.f);
                    #pragma unroll
                    for (int kx = 0; kx < 3; kx++) {
                        float xv = fmaf((float)(iw0 + kx), sx, -1.f);
                        float m = mh[ky]*mw[kx];
                        axv = fmaf(dw1[18 + ky*3 + kx], m * xv, axv);
                        ayv = fmaf(dw1[27 + ky*3 + kx], m * yv, ayv);
                        arv = fmaf(dw1[36 + ky*3 + kx], m * (xv*xv + yv*yv), arv);
                    }
                }
                dd[i][2] = axv; dd[i][3] = ayv; dd[i][4] = arv;
            }
        }
    }

    // ---- chunked A2 (f1 -> LDS) + B (dw2 + pw2) ----
    v2f acc2[32];
    #pragma unroll
    for (int o = 0; o < 32; o++) acc2[o] = *(const v2f*)(b2 + 2*o);

    const int lr = t >> 5, lc = t & 31;        // this thread's f2 pixel in tile
    const int rbase = 2*lr*LROW + lc;          // swizzled LDS base for taps

    if (interior)
        fuse12_chunks<false>(t, dd, vmf, widx, f1buf, wb, b1, dw2, rbase, acc2);
    else
        fuse12_chunks<true>(t, dd, vmf, widx, f1buf, wb, b1, dw2, rbase, acc2);

    const int oh = oh0 + lr, ow = ow0 + lc;
    size_t obase = ((size_t)b * 64) * (H2*W2) + (size_t)oh * W2 + ow;
    #pragma unroll
    for (int o = 0; o < 32; o++) {
        float va = acc2[o].x, vb2 = acc2[o].y;
        out[obase + (size_t)(2*o)   * (H2*W2)] = va  > 0.f ? va  : (__expf(va)  - 1.f);
        out[obase + (size_t)(2*o+1) * (H2*W2)] = vb2 > 0.f ? vb2 : (__expf(vb2) - 1.f);
    }
}

// ---------------- K3: dwsep3 + ELU + fused attention logits ------------------
// r8 form: packed pw3, no explicit pipeline (r4: +33us), no channel split
// (r11: +27us), NCHW taps (r12 NHWC: L1 thrash, +50us rest). Attn 1x1 logit
// dot in the epilogue from register values.
__global__ __launch_bounds__(256, 4) void k_stage3(
    const float* __restrict__ in, const float* __restrict__ dw3,
    const float* __restrict__ b3, const float* __restrict__ wb,
    const float* __restrict__ attn_w, const float* __restrict__ attn_b,
    float* __restrict__ out, float* __restrict__ lg)
{
    int idx = blockIdx.x * 256 + threadIdx.x;     // 153,600 exact
    int ow = idx % W3; int tmp = idx / W3; int oh = tmp % H3; int b = tmp / H3;
    int ih0 = 2*oh - 1, iw0 = 2*ow - 1;
    float mh[3] = { ih0 >= 0 ? 1.f : 0.f, 1.f, 1.f };
    float mw[3] = { iw0 >= 0 ? 1.f : 0.f, 1.f, 1.f };
    int ihx[3] = { ih0 < 0 ? 0 : ih0, ih0 + 1, ih0 + 2 };
    int iwx[3] = { iw0 < 0 ? 0 : iw0, iw0 + 1, iw0 + 2 };
    float m9[9];
    int off[9];
    #pragma unroll
    for (int ky = 0; ky < 3; ky++)
        #pragma unroll
        for (int kx = 0; kx < 3; kx++) {
            m9[ky*3 + kx] = mh[ky] * mw[kx];
            off[ky*3 + kx] = ihx[ky]*W2 + iwx[kx];
        }

    v2f acc2[32];
    #pragma unroll
    for (int o = 0; o < 32; o++) acc2[o] = *(const v2f*)(b3 + 2*o);

    const float* inb = in + (size_t)b * F2_PB;
    for (int c = 0; c < 64; c++) {
        const float* g = inb + (size_t)c * (H2*W2);
        const float* w9 = dw3 + c*9;               // uniform
        float dv = 0.f;
        #pragma unroll
        for (int p = 0; p < 9; p++)
            dv = fmaf(w9[p], m9[p] * g[off[p]], dv);
        const v2f* wr2 = (const v2f*)(wb + W_PW3T + c*64);  // uniform
        v2f dvv = { dv, dv };
        #pragma unroll
        for (int o = 0; o < 32; o++)
            acc2[o] = __builtin_elementwise_fma(wr2[o], dvv, acc2[o]);  // v_pk_fma_f32
    }

    size_t obase = ((size_t)b * 64) * (H3*W3) + (size_t)oh*W3 + ow;
    float logit = attn_b[0];
    #pragma unroll
    for (int o = 0; o < 32; o++) {
        float va = acc2[o].x, vb2 = acc2[o].y;
        float ea = va  > 0.f ? va  : (__expf(va)  - 1.f);
        float eb = vb2 > 0.f ? vb2 : (__expf(vb2) - 1.f);
        out[obase + (size_t)(2*o)  *(H3*W3)] = ea;
        out[obase + (size_t)(2*o+1)*(H3*W3)] = eb;
        logit = fmaf(attn_w[2*o],   ea, logit);    // attn_w: uniform s_loads
        logit = fmaf(attn_w[2*o+1], eb, logit);
    }
    lg[b*N3 + oh*W3 + ow] = logit;                 // coalesced per wave
}

// ---------------- K4a: per-batch softmax over logits ------------------------
__global__ __launch_bounds__(256) void k_softmax(
    float* __restrict__ lg, float* __restrict__ invs)
{
    int b = blockIdx.x, t = threadIdx.x;
    int lane = t & 63, wid = t >> 6;       // 4 waves
    __shared__ float sm[4], ss[4];
    float* base = lg + b*N3;

    float m = -1e30f;
    for (int n = t; n < N3; n += 256) m = fmaxf(m, base[n]);
    #pragma unroll
    for (int o = 32; o; o >>= 1) m = fmaxf(m, __shfl_down(m, o, 64));
    if (lane == 0) sm[wid] = m;
    __syncthreads();
    m = fmaxf(fmaxf(sm[0], sm[1]), fmaxf(sm[2], sm[3]));

    float s = 0.f;
    for (int n = t; n < N3; n += 256) {
        float e = __expf(base[n] - m);
        base[n] = e;
        s += e;
    }
    #pragma unroll
    for (int o = 32; o; o >>= 1) s += __shfl_down(s, o, 64);
    if (lane == 0) ss[wid] = s;
    __syncthreads();
    if (t == 0) invs[b] = 1.f / (ss[0] + ss[1] + ss[2] + ss[3]);
}

// ---------------- K4b: attention pooling, one block per (b,c) ---------------
__global__ __launch_bounds__(256) void k_pool(
    const float* __restrict__ f3, const float* __restrict__ lg,
    const float* __restrict__ invs, float* __restrict__ pooled)
{
    int bc = blockIdx.x;           // b*64 + c
    int b = bc >> 6, c = bc & 63;
    int t = threadIdx.x, lane = t & 63, wid = t >> 6;
    __shared__ float sr[4];

    const float4* f = (const float4*)(f3 + (size_t)b * F3_PB + (size_t)c * N3);
    const float4* w = (const float4*)(lg + b*N3);

    float s = 0.f;
    for (int i = t; i < N3/4; i += 256) {
        float4 a = f[i], e = w[i];
        s = fmaf(a.x, e.x, s); s = fmaf(a.y, e.y, s);
        s = fmaf(a.z, e.z, s); s = fmaf(a.w, e.w, s);
    }
    #pragma unroll
    for (int o = 32; o; o >>= 1) s += __shfl_down(s, o, 64);
    if (lane == 0) sr[wid] = s;
    __syncthreads();
    if (t == 0) pooled[bc] = (sr[0] + sr[1] + sr[2] + sr[3]) * invs[b];
}

// ---------------- K4c: MLP + GRU tail, one wave per batch -------------------
__global__ __launch_bounds__(64) void k_tail(
    const float* __restrict__ pooled,
    const float* __restrict__ mlp1_w, const float* __restrict__ mlp1_b,
    const float* __restrict__ mlp2_w, const float* __restrict__ mlp2_b,
    const float* __restrict__ w_ih, const float* __restrict__ b_ih,
    const float* __restrict__ b_hh,
    const float* __restrict__ fc_w, const float* __restrict__ fc_b,
    float* __restrict__ out)
{
    __shared__ float s_pooled[64];
    __shared__ float s_h1[32];
    __shared__ float s_om[3];
    __shared__ float s_h[32];
    int t = threadIdx.x, b = blockIdx.x;

    s_pooled[t] = pooled[b*64 + t];
    __syncthreads();

    if (t < 32) {
        float a = mlp1_b[t];
        #pragma unroll 8
        for (int c = 0; c < 64; c++) a = fmaf(mlp1_w[t*64 + c], s_pooled[c], a);
        s_h1[t] = a > 0.f ? a : (__expf(a) - 1.f);
    }
    __syncthreads();
    if (t < 3) {
        float a = mlp2_b[t];
        for (int j = 0; j < 32; j++) a = fmaf(mlp2_w[t*32 + j], s_h1[j], a);
        s_om[t] = a;
    }
    __syncthreads();
    if (t < 32) {
        float gr = b_ih[t], gz = b_ih[32 + t], gn = b_ih[64 + t];
        #pragma unroll
        for (int k = 0; k < 3; k++) {
            float ok = s_om[k];
            gr = fmaf(w_ih[t*3 + k],        ok, gr);
            gz = fmaf(w_ih[(32 + t)*3 + k], ok, gz);
            gn = fmaf(w_ih[(64 + t)*3 + k], ok, gn);
        }
        float hr = b_hh[t], hz = b_hh[32 + t], hn = b_hh[64 + t];
        float r = 1.f / (1.f + __expf(-(gr + hr)));
        float z = 1.f / (1.f + __expf(-(gz + hz)));
        float nn = tanhf(gn + r * hn);
        s_h[t] = (1.f - z) * nn;
    }
    __syncthreads();
    if (t < 3) {
        float dl = fc_b[t];
        for (int j = 0; j < 32; j++) dl = fmaf(fc_w[t*32 + j], s_h[j], dl);
        out[b*3 + t] = s_om[t] + dl;
    }
}

// ---------------- host ----------------
extern "C" void kernel_launch(void* const* d_in, const int* in_sizes, int n_in,
                              void* d_out, int out_size, void* d_ws, size_t ws_size,
                              hipStream_t stream)
{
    const float* flow = (const float*)d_in[0];
    float* wb = (float*)d_ws;

    // layout: [wbuf][f2 x32][f3 x32][logits 32x4800][invS 32][pooled 32*64]
    float* f2     = (float*)((char*)d_ws + WBUF_BYTES);
    float* f3     = f2 + (size_t)32 * F2_PB;
    float* lg     = f3 + (size_t)32 * F3_PB;
    float* invs   = lg + (size_t)32 * N3;
    float* pooled = invs + 32;

    k_cvt<<<1, 256, 0, stream>>>(
        (const float*)d_in[2], (const float*)d_in[5], (const float*)d_in[8], wb);

    // fused stage1+stage2: one block per 32x8 f2 tile
    k_fuse12<<<32 * TILES_PB, 256, 0, stream>>>(
        flow, (const float*)d_in[1], (const float*)d_in[3],
        (const float*)d_in[4], (const float*)d_in[6], wb, f2);

    // stage3 + fused attn logits: one thread per f3 pixel
    k_stage3<<<(32*H3*W3)/256, 256, 0, stream>>>(
        f2, (const float*)d_in[7], (const float*)d_in[9], wb,
        (const float*)d_in[10], (const float*)d_in[11], f3, lg);

    k_softmax<<<32, 256, 0, stream>>>(lg, invs);

    k_pool<<<32*64, 256, 0, stream>>>(f3, lg, invs, pooled);

    k_tail<<<32, 64, 0, stream>>>(pooled,
        (const float*)d_in[12], (const float*)d_in[13],
        (const float*)d_in[14], (const float*)d_in[15],
        (const float*)d_in[16], (const float*)d_in[18],
        (const float*)d_in[19], (const float*)d_in[20],
        (const float*)d_in[21], (float*)d_out);
}